// Round 2
// baseline (358.817 us; speedup 1.0000x reference)
//
#include <hip/hip_runtime.h>
#include <hip/hip_bf16.h>

#define N_HEAD 8
#define D_MODEL 512
#define D_HEAD 64
#define D_HIDDEN 2048
#define NTOK 64
#define BATCH 4096

typedef __attribute__((ext_vector_type(4))) float f32x4;
typedef __attribute__((ext_vector_type(8))) short short8;
typedef __attribute__((ext_vector_type(8))) unsigned short u16x8;

__device__ __forceinline__ float bf2f(unsigned short u) {
    return __uint_as_float(((unsigned int)u) << 16);
}
__device__ __forceinline__ unsigned short f2bf(float f) {
    unsigned int b = __float_as_uint(f);
    b += 0x7fffu + ((b >> 16) & 1u);
    return (unsigned short)(b >> 16);
}
__device__ __forceinline__ float wave_sum(float v) {
    v += __shfl_xor(v, 32); v += __shfl_xor(v, 16); v += __shfl_xor(v, 8);
    v += __shfl_xor(v, 4);  v += __shfl_xor(v, 2);  v += __shfl_xor(v, 1);
    return v;
}
__device__ __forceinline__ void gload_lds16(const void* g, void* l) {
    __builtin_amdgcn_global_load_lds(
        (const __attribute__((address_space(1))) unsigned int*)g,
        (__attribute__((address_space(3))) unsigned int*)l, 16, 0, 0);
}

// ---------------------------------------------------------------------------
// K0: merged prep. y=0..2: transpose {Wv,W1,W2} f32 -> bf16 (N x K); y=3: u,c0
// ---------------------------------------------------------------------------
__global__ __launch_bounds__(256) void prep_all(
    const float* __restrict__ Wk, const float* __restrict__ score_w,
    const float* __restrict__ bk, const float* __restrict__ score_b,
    const float* __restrict__ Wv, const float* __restrict__ W1,
    const float* __restrict__ W2,
    float* __restrict__ u, float* __restrict__ c0,
    unsigned short* __restrict__ WvT, unsigned short* __restrict__ W1T,
    unsigned short* __restrict__ W2T) {
    int m = blockIdx.y;
    if (m == 3) {
        int tid = blockIdx.x * 256 + threadIdx.x;
        if (blockIdx.x < 16) {
            int c = tid >> 3, h = tid & 7;
            float s = 0.f;
            #pragma unroll 8
            for (int d = 0; d < D_HEAD; ++d)
                s += Wk[c * D_MODEL + h * D_HEAD + d] * score_w[h * D_HEAD + d];
            u[c * N_HEAD + h] = s;
        }
        if (blockIdx.x == 0 && threadIdx.x < N_HEAD) {
            int h = threadIdx.x;
            float s = score_b[h];
            for (int d = 0; d < D_HEAD; ++d)
                s += bk[h * D_HEAD + d] * score_w[h * D_HEAD + d];
            c0[h] = s;
        }
        return;
    }
    const float* in; unsigned short* out; int K, N, tX, tiles;
    if (m == 0)      { in = Wv; out = WvT; K = 512;  N = 512;  tX = 16; tiles = 256;  }
    else if (m == 1) { in = W1; out = W1T; K = 512;  N = 2048; tX = 64; tiles = 1024; }
    else             { in = W2; out = W2T; K = 2048; N = 512;  tX = 16; tiles = 1024; }
    int t = blockIdx.x;
    if (t >= tiles) return;
    int n0 = (t % tX) * 32, k0 = (t / tX) * 32;
    __shared__ float tile[32][33];
    int tx = threadIdx.x & 31, ty = threadIdx.x >> 5;
    #pragma unroll
    for (int i = ty; i < 32; i += 8)
        tile[i][tx] = in[(size_t)(k0 + i) * N + n0 + tx];
    __syncthreads();
    #pragma unroll
    for (int i = ty; i < 32; i += 8)
        out[(size_t)(n0 + i) * K + k0 + tx] = f2bf(tile[tx][i]);
}

// ---------------------------------------------------------------------------
// K1: fused scores + softmax + pool, single pass over x (no max subtraction:
// |score| < ~0.5 so exp is exact-safe in fp32).
// Block = 1 batch, 4 waves x 16 rows. Lane owns channels l*8..l*8+7.
// ---------------------------------------------------------------------------
__global__ __launch_bounds__(256) void score_pool_fused(
    const float* __restrict__ x, const float* __restrict__ u,
    const float* __restrict__ c0, unsigned short* __restrict__ pooled) {
    __shared__ float red[3][64][65];   // waves 1..3 partial accs (stride 65: conflict-free)
    __shared__ float zred[4][8];
    int b = blockIdx.x;
    int tid = threadIdx.x, l = tid & 63, w = tid >> 6;
    const float* xb = x + (size_t)b * NTOK * D_MODEL;

    float ureg[64];
    {
        const float4* up = (const float4*)(u) + (size_t)l * 16;
        #pragma unroll
        for (int j = 0; j < 16; ++j) {
            float4 v = up[j];
            ureg[j * 4 + 0] = v.x; ureg[j * 4 + 1] = v.y;
            ureg[j * 4 + 2] = v.z; ureg[j * 4 + 3] = v.w;
        }
    }
    float c0r[8];
    #pragma unroll
    for (int h = 0; h < 8; ++h) c0r[h] = c0[h];

    float acc[64];
    #pragma unroll
    for (int i = 0; i < 64; ++i) acc[i] = 0.f;
    float Z[8] = {0, 0, 0, 0, 0, 0, 0, 0};

    // 2 rows per iter, software-pipelined loads
    const float* rp = xb + (size_t)(w * 16) * D_MODEL + l * 8;
    float4 nx0 = *(const float4*)(rp);
    float4 nx1 = *(const float4*)(rp + 4);
    float4 ny0 = *(const float4*)(rp + D_MODEL);
    float4 ny1 = *(const float4*)(rp + D_MODEL + 4);
    for (int it = 0; it < 8; ++it) {
        float4 x0 = nx0, x1 = nx1, y0 = ny0, y1 = ny1;
        if (it < 7) {
            rp += 2 * D_MODEL;
            nx0 = *(const float4*)(rp);
            nx1 = *(const float4*)(rp + 4);
            ny0 = *(const float4*)(rp + D_MODEL);
            ny1 = *(const float4*)(rp + D_MODEL + 4);
        }
        float xv0[8] = {x0.x, x0.y, x0.z, x0.w, x1.x, x1.y, x1.z, x1.w};
        float xv1[8] = {y0.x, y0.y, y0.z, y0.w, y1.x, y1.y, y1.z, y1.w};
        float p0[8] = {0, 0, 0, 0, 0, 0, 0, 0};
        float p1[8] = {0, 0, 0, 0, 0, 0, 0, 0};
        #pragma unroll
        for (int i = 0; i < 8; ++i)
            #pragma unroll
            for (int h = 0; h < 8; ++h) {
                p0[h] += xv0[i] * ureg[i * 8 + h];
                p1[h] += xv1[i] * ureg[i * 8 + h];
            }
        #pragma unroll
        for (int h = 0; h < 8; ++h) { p0[h] = wave_sum(p0[h]); p1[h] = wave_sum(p1[h]); }
        #pragma unroll
        for (int h = 0; h < 8; ++h) {
            float e0 = __expf(p0[h] + c0r[h]);
            float e1 = __expf(p1[h] + c0r[h]);
            Z[h] += e0 + e1;
            #pragma unroll
            for (int i = 0; i < 8; ++i)
                acc[h * 8 + i] += e0 * xv0[i] + e1 * xv1[i];
        }
    }

    if (w) {
        #pragma unroll
        for (int j = 0; j < 16; ++j)
            *(f32x4*)&red[w - 1][l][j * 4] = *(const f32x4*)&acc[j * 4];
    }
    if (l < 8) zred[w][l] = Z[l];
    __syncthreads();
    if (w == 0) {
        float Zt[8];
        #pragma unroll
        for (int h = 0; h < 8; ++h)
            Zt[h] = Z[h] + zred[1][h] + zred[2][h] + zred[3][h];
        #pragma unroll
        for (int ww = 0; ww < 3; ++ww)
            #pragma unroll
            for (int j = 0; j < 16; ++j) {
                f32x4 v = *(const f32x4*)&red[ww][l][j * 4];
                acc[j * 4 + 0] += v[0]; acc[j * 4 + 1] += v[1];
                acc[j * 4 + 2] += v[2]; acc[j * 4 + 3] += v[3];
            }
        unsigned short* pb = pooled + (size_t)b * N_HEAD * D_MODEL;
        #pragma unroll
        for (int h = 0; h < 8; ++h) {
            float inv = 1.f / Zt[h];
            u16x8 o;
            #pragma unroll
            for (int i = 0; i < 8; ++i) o[i] = f2bf(acc[h * 8 + i] * inv);
            *(u16x8*)(pb + (size_t)h * D_MODEL + l * 8) = o;
        }
    }
}

// ---------------------------------------------------------------------------
// MFMA GEMM, global_load_lds staging with XOR-swizzled LDS (swizzle applied on
// the global SOURCE address since gload_lds writes linearly; reads apply the
// same XOR).  C tile BM x BN, 4 waves (2x2).  A: row-major [M][lda] bf16.
// BT: [N][K] bf16.  MODE 0: per-head (grid.y=head, N=64), bf16 out +bias.
// MODE 1: bf16 out, gelu(+bias).  MODE 2: f32 out, +bias +residual(bf16).
// ---------------------------------------------------------------------------
template <int BM, int BN, int MODE>
__global__ __launch_bounds__(256) void gemm_mf(
    const unsigned short* __restrict__ A, int lda,
    const unsigned short* __restrict__ BT,
    const float* __restrict__ bias,
    void* __restrict__ Cout, int ldc,
    const unsigned short* __restrict__ res, int K) {
    __shared__ unsigned short Al[BM * 64];
    __shared__ unsigned short Bl[BN * 64];
    int m0 = blockIdx.x * BM;
    int n0;
    const unsigned short* Ap = A;
    const unsigned short* Bp;
    const float* bp;
    if (MODE == 0) {
        int h = blockIdx.y;
        Ap = A + (size_t)h * 512;
        Bp = BT + (size_t)h * 64 * K;
        bp = bias + h * 64;
        n0 = h * 64;
    } else {
        n0 = blockIdx.y * BN;
        Bp = BT + (size_t)n0 * K;
        bp = bias + n0;
    }
    int tid = threadIdx.x, l = tid & 63, w = tid >> 6;
    int lr = l & 15, lq = l >> 4;
    int wm = w >> 1, wn = w & 1;
    constexpr int MR = BM / 32, NR = BN / 32;
    constexpr int AI = BM / 8, BI = BN / 8;  // 1024B staging insts total

    f32x4 acc[MR][NR];
    #pragma unroll
    for (int mi = 0; mi < MR; ++mi)
        #pragma unroll
        for (int nj = 0; nj < NR; ++nj) acc[mi][nj] = (f32x4){0.f, 0.f, 0.f, 0.f};

    int srow = l >> 3;                               // row within 8-row group
    int scol = ((l & 7) ^ ((l >> 3) & 7)) << 3;      // pre-swizzled k-offset (elems)

    for (int k0 = 0; k0 < K; k0 += 64) {
        #pragma unroll
        for (int j = 0; j < AI / 4; ++j) {
            int ji = w * (AI / 4) + j;
            const unsigned short* src = Ap + (size_t)(m0 + ji * 8 + srow) * lda + k0 + scol;
            gload_lds16(src, &Al[ji * 512]);
        }
        #pragma unroll
        for (int j = 0; j < BI / 4; ++j) {
            int ji = w * (BI / 4) + j;
            const unsigned short* src = Bp + (size_t)(ji * 8 + srow) * K + k0 + scol;
            gload_lds16(src, &Bl[ji * 512]);
        }
        __syncthreads();
        #pragma unroll
        for (int kk = 0; kk < 64; kk += 32) {
            int sw = (kk + lq * 8) ^ ((l & 7) << 3);
            short8 af[MR], bf[NR];
            #pragma unroll
            for (int mi = 0; mi < MR; ++mi)
                af[mi] = *(const short8*)&Al[(wm * (BM / 2) + mi * 16 + lr) * 64 + sw];
            #pragma unroll
            for (int nj = 0; nj < NR; ++nj)
                bf[nj] = *(const short8*)&Bl[(wn * (BN / 2) + nj * 16 + lr) * 64 + sw];
            #pragma unroll
            for (int mi = 0; mi < MR; ++mi)
                #pragma unroll
                for (int nj = 0; nj < NR; ++nj)
                    acc[mi][nj] = __builtin_amdgcn_mfma_f32_16x16x32_bf16(
                        af[mi], bf[nj], acc[mi][nj], 0, 0, 0);
        }
        __syncthreads();
    }

    #pragma unroll
    for (int mi = 0; mi < MR; ++mi) {
        #pragma unroll
        for (int nj = 0; nj < NR; ++nj) {
            #pragma unroll
            for (int j = 0; j < 4; ++j) {
                int row = m0 + wm * (BM / 2) + mi * 16 + lq * 4 + j;
                int nl = wn * (BN / 2) + nj * 16 + lr;
                int col = n0 + nl;
                float v = acc[mi][nj][j] + bp[nl];
                if (MODE == 1) {
                    v = 0.5f * v * (1.0f + erff(v * 0.70710678118654752f));
                }
                if (MODE == 2) {
                    v += bf2f(res[(size_t)row * 512 + col]);
                    ((float*)Cout)[(size_t)row * ldc + col] = v;
                } else {
                    ((unsigned short*)Cout)[(size_t)row * ldc + col] = f2bf(v);
                }
            }
        }
    }
}

// ---------------------------------------------------------------------------
// K5: in-place LayerNorm over 512, one wave per row
// ---------------------------------------------------------------------------
__global__ __launch_bounds__(256) void ln_kernel(
    float* __restrict__ y, const float* __restrict__ g, const float* __restrict__ bta) {
    int row = blockIdx.x * 4 + (threadIdx.x >> 6);
    int l = threadIdx.x & 63;
    float* yp = y + (size_t)row * D_MODEL;
    float4 v0 = *(const float4*)(yp + l * 8);
    float4 v1 = *(const float4*)(yp + l * 8 + 4);
    float vv[8] = {v0.x, v0.y, v0.z, v0.w, v1.x, v1.y, v1.z, v1.w};
    float s = 0.f;
    #pragma unroll
    for (int i = 0; i < 8; ++i) s += vv[i];
    s = wave_sum(s);
    float mean = s * (1.f / 512.f);
    float q = 0.f;
    #pragma unroll
    for (int i = 0; i < 8; ++i) { float d = vv[i] - mean; q += d * d; }
    q = wave_sum(q);
    float rstd = rsqrtf(q * (1.f / 512.f) + 1e-5f);
    float4 g0 = *(const float4*)(g + l * 8);
    float4 g1 = *(const float4*)(g + l * 8 + 4);
    float4 b0 = *(const float4*)(bta + l * 8);
    float4 b1 = *(const float4*)(bta + l * 8 + 4);
    float gv[8] = {g0.x, g0.y, g0.z, g0.w, g1.x, g1.y, g1.z, g1.w};
    float bv[8] = {b0.x, b0.y, b0.z, b0.w, b1.x, b1.y, b1.z, b1.w};
    float ov[8];
    #pragma unroll
    for (int i = 0; i < 8; ++i) ov[i] = (vv[i] - mean) * rstd * gv[i] + bv[i];
    float4 o0 = {ov[0], ov[1], ov[2], ov[3]};
    float4 o1 = {ov[4], ov[5], ov[6], ov[7]};
    *(float4*)(yp + l * 8) = o0;
    *(float4*)(yp + l * 8 + 4) = o1;
}

extern "C" void kernel_launch(void* const* d_in, const int* in_sizes, int n_in,
                              void* d_out, int out_size, void* d_ws, size_t ws_size,
                              hipStream_t stream) {
    const float* x       = (const float*)d_in[0];
    const float* Wk      = (const float*)d_in[1];
    const float* bk      = (const float*)d_in[2];
    const float* Wv      = (const float*)d_in[3];
    const float* bv      = (const float*)d_in[4];
    const float* score_w = (const float*)d_in[5];
    const float* score_b = (const float*)d_in[6];
    const float* W1      = (const float*)d_in[7];
    const float* b1      = (const float*)d_in[8];
    const float* W2      = (const float*)d_in[9];
    const float* b2      = (const float*)d_in[10];
    const float* ln_g    = (const float*)d_in[11];
    const float* ln_b    = (const float*)d_in[12];
    float* out = (float*)d_out;

    char* ws = (char*)d_ws;
    size_t off = 0;
    auto alloc = [&](size_t sz) {
        void* p = ws + off;
        off = (off + sz + 1023) & ~(size_t)1023;
        return p;
    };
    float* u            = (float*)alloc((size_t)D_MODEL * N_HEAD * 4);
    float* c0           = (float*)alloc(N_HEAD * 4);
    unsigned short* WvT = (unsigned short*)alloc((size_t)512 * 512 * 2);
    unsigned short* W1T = (unsigned short*)alloc((size_t)2048 * 512 * 2);
    unsigned short* W2T = (unsigned short*)alloc((size_t)512 * 2048 * 2);
    unsigned short* pooled = (unsigned short*)alloc((size_t)BATCH * N_HEAD * D_MODEL * 2);
    unsigned short* feat   = (unsigned short*)alloc((size_t)BATCH * D_MODEL * 2);
    unsigned short* Hbuf   = (unsigned short*)alloc((size_t)BATCH * D_HIDDEN * 2);

    prep_all<<<dim3(1024, 4), dim3(256), 0, stream>>>(
        Wk, score_w, bk, score_b, Wv, W1, W2, u, c0, WvT, W1T, W2T);
    score_pool_fused<<<dim3(BATCH), dim3(256), 0, stream>>>(x, u, c0, pooled);
    // proj: feature = pooled @ blockdiag(Wv per head) + bv
    gemm_mf<128, 64, 0><<<dim3(32, 8), dim3(256), 0, stream>>>(
        pooled, N_HEAD * D_MODEL, WvT, bv, (void*)feat, D_MODEL,
        (const unsigned short*)nullptr, 512);
    // ffn1: H = gelu(feature @ W1 + b1)
    gemm_mf<128, 128, 1><<<dim3(32, 16), dim3(256), 0, stream>>>(
        feat, D_MODEL, W1T, b1, (void*)Hbuf, D_HIDDEN,
        (const unsigned short*)nullptr, 512);
    // ffn2: y = H @ W2 + b2 + feature  (f32 -> d_out)
    gemm_mf<64, 128, 2><<<dim3(64, 4), dim3(256), 0, stream>>>(
        Hbuf, D_HIDDEN, W2T, b2, (void*)out, D_MODEL, feat, 2048);
    ln_kernel<<<dim3(1024), dim3(256), 0, stream>>>(out, ln_g, ln_b);
}